// Round 1
// baseline (411.957 us; speedup 1.0000x reference)
//
#include <hip/hip_runtime.h>

// out[b,o] = sum_i W[i,o] * I[i,b],  I = concat per object [first|mid0|mid1|last]
// ROWS = 17408 = 136 blocks of 128 rows; each 128-block lies in exactly one
// source segment (offsets 0,128,4224,4352 are all multiples of 128).
// Memory-bound: 285 MB of I must stream once -> ~45us floor at 6.3 TB/s.

#define BATCH  4096
#define OUTC   32
#define NCHUNK 34          // 136 row-blocks / 4 per chunk -> 512 rows per block

// Block = 256 threads = 4 waves. All 4 waves share the same 64 b-lanes
// (coalesced 256B global loads of I); wave w owns o-slice [8w, 8w+8) so
// weight loads are wave-uniform (scalar s_load path) and acc is 8 VGPRs.
__global__ __launch_bounds__(256) void cwl_partial(
    const float* __restrict__ cf,   // (4,128,4096)
    const float* __restrict__ cm,   // (4,2,2048,4096) == (4,4096,4096)
    const float* __restrict__ cl,   // (4,128,4096)
    const float* __restrict__ w,    // (17408,32)
    float* __restrict__ ws)         // (NCHUNK,4096,32) partials
{
    const int btile = blockIdx.x & 63;        // 64 b-tiles of 64
    const int chunk = blockIdx.x >> 6;        // 0..33
    const int lane  = threadIdx.x & 63;
    const int wv    = threadIdx.x >> 6;       // 0..3
    // force wave-uniform o-offset into an SGPR so weight loads go scalar
    const int o0    = __builtin_amdgcn_readfirstlane(wv * 8);
    const int b     = btile * 64 + lane;

    float acc[8];
#pragma unroll
    for (int k = 0; k < 8; ++k) acc[k] = 0.0f;

    for (int s = 0; s < 4; ++s) {
        const int m = chunk * 4 + s;          // global 128-row block, 0..135
        const int c = m / 34;                 // TT object
        const int j = m - c * 34;             // block within object, 0..33
        const float* src;
        if (j == 0)
            src = cf + (size_t)c * 128 * BATCH;
        else if (j == 33)
            src = cl + (size_t)c * 128 * BATCH;
        else
            src = cm + ((size_t)c * 4096 + (size_t)(j - 1) * 128) * BATCH;

        const float* xp = src + b;
        const float* wp = w + (size_t)m * 128 * OUTC + o0;   // uniform

#pragma unroll 8
        for (int r = 0; r < 128; ++r) {
            const float x = xp[(size_t)r * BATCH];           // coalesced 256B/wave
#pragma unroll
            for (int k = 0; k < 8; ++k)
                acc[k] = fmaf(x, wp[r * OUTC + k], acc[k]);  // s_load_dwordx8 weights
        }
    }

    // ws[chunk][b][o]: 8 consecutive floats per lane -> 2KB contiguous per wave
    float4* dst = (float4*)(ws + ((size_t)chunk * BATCH + b) * OUTC + o0);
    dst[0] = make_float4(acc[0], acc[1], acc[2], acc[3]);
    dst[1] = make_float4(acc[4], acc[5], acc[6], acc[7]);
}

// out[idx] = sum_c ws[c][idx], idx = b*32+o. Reads and writes fully coalesced.
__global__ __launch_bounds__(256) void cwl_reduce(
    const float* __restrict__ ws, float* __restrict__ out)
{
    const int idx = blockIdx.x * 256 + threadIdx.x;   // 0..131071
    float s = 0.0f;
#pragma unroll
    for (int c = 0; c < NCHUNK; ++c)
        s += ws[(size_t)c * (BATCH * OUTC) + idx];
    out[idx] = s;
}

extern "C" void kernel_launch(void* const* d_in, const int* in_sizes, int n_in,
                              void* d_out, int out_size, void* d_ws, size_t ws_size,
                              hipStream_t stream)
{
    const float* cf = (const float*)d_in[0];
    const float* cm = (const float*)d_in[1];
    const float* cl = (const float*)d_in[2];
    const float* w  = (const float*)d_in[3];
    float* out = (float*)d_out;
    float* ws  = (float*)d_ws;   // needs 34*131072*4 = 17.8 MB

    cwl_partial<<<dim3(64 * NCHUNK), dim3(256), 0, stream>>>(cf, cm, cl, w, ws);
    cwl_reduce<<<dim3((BATCH * OUTC) / 256), dim3(256), 0, stream>>>(ws, out);
}